// Round 2
// baseline (129.125 us; speedup 1.0000x reference)
//
#include <hip/hip_runtime.h>
#include <hip/hip_bf16.h>
#include <math.h>

// Problem dims (fixed by reference)
#define B_ROWS 8192
#define D_IN   256
#define H1_DIM 512
#define H2_DIM 256
#define D_OUT  64
#define EPSF   1e-12f
#define THRESH 0.9f
// hh-only gram screen: |fid_hh - fid_true| < 0.008 for unit vectors
// -> decisions outside (0.89, 0.91) are certain; band hits get exact refine.
#define BAND_LO 0.89f
#define BAND_HI 0.91f

typedef __attribute__((ext_vector_type(8))) short short8;   // 8 bf16 = 4 VGPR
typedef __attribute__((ext_vector_type(4))) float f32x4;

// fast tanh via hardware exp: tanh(|x|) = (1-e^{-2|x|})/(1+e^{-2|x|}), ~1e-7 rel err
__device__ inline float tanh_fast(float xx) {
  const float ax = fabsf(xx);
  const float t = __expf(-2.0f * ax);
  const float r = (1.0f - t) / (1.0f + t);
  return xx < 0.0f ? -r : r;
}

// split fp32x8 -> bf16 hi + bf16 mid (residual), fragment-packed
__device__ inline void splitf8(float4 a, float4 b, short8& h, short8& m) {
  float v[8] = {a.x, a.y, a.z, a.w, b.x, b.y, b.z, b.w};
  short h8[8], m8[8];
#pragma unroll
  for (int e = 0; e < 8; ++e) {
    __hip_bfloat16 hb = __float2bfloat16(v[e]);
    float hf = __bfloat162float(hb);
    __hip_bfloat16 mb = __float2bfloat16(v[e] - hf);
    h8[e] = *(short*)&hb;
    m8[e] = *(short*)&mb;
  }
  h = *(short8*)h8;
  m = *(short8*)m8;
}

// ---------------- fully fused MLP ----------------
// One block = 32 rows of the batch. 8 waves, 512 threads, 1 block/CU (LDS 129KB).
// All weights read fp32 directly from global (L2-resident) and split to
// (hi,mid) bf16 in-register — same bytes as pre-packed, no pack kernel.
// h1/h2 never touch HBM: accumulators -> wbuf (LDS fp32) -> split-pack frag LDS.
// K-loops have NO barriers (A read-only in LDS, B from global) -> compiler
// pipelines weight loads freely; barriers only separate the 3 layer phases.
// Fragment conventions (verified in prior rounds):
//   A/B frag: row = tile*16 + (lane&15), k = q*32 + (lane>>4)*8 + e
//   C/D:      col = lane&15, row = (lane>>4)*4 + r
__global__ __launch_bounds__(512, 2)
void fused_mlp(const float* __restrict__ x,  const float* __restrict__ W1,
               const float* __restrict__ b1, const float* __restrict__ W2,
               const float* __restrict__ b2, const float* __restrict__ W3,
               const float* __restrict__ b3, float* __restrict__ out,
               short* __restrict__ vph, short* __restrict__ vpm,
               float* __restrict__ res) {
  constexpr int WC = 260;   // wbuf col stride (pad vs 256)
  __shared__ __align__(16) union {
    struct { short h[8192]; short m[8192]; } xp;   // layer1 A frags (32x256)
    struct { short h[8192]; short m[8192]; } h2p;  // layer3 A frags (32x256)
  } uAB;                                           // 32 KB
  __shared__ __align__(16) short h1h[16384];       // 32 KB (32x512 hi)
  __shared__ __align__(16) short h1m[16384];       // 32 KB (32x512 mid)
  __shared__ __align__(16) float wbuf[32 * WC];    // 33 KB epilogue transpose
  __shared__ float nsum[32];
  __shared__ float invn[32];

  const int tid = threadIdx.x;
  const int wave = tid >> 6, lane = tid & 63;
  const int r0 = blockIdx.x * 32;
  const int col16 = lane & 15;       // frag row-within-tile
  const int k8 = (lane >> 4) << 3;   // frag k-offset
  const int rbase = (lane >> 4) * 2 * 2;  // C-layout row base = (lane>>4)*4

  // zero this block's res rows (harness poisons res)
  {
    float4* rz = (float4*)(res + (size_t)r0 * D_OUT);
    rz[tid] = make_float4(0.f, 0.f, 0.f, 0.f);
  }

  // ---- phase X: load x block (32x256 fp32), split-pack to frag LDS ----
#pragma unroll
  for (int uu = 0; uu < 2; ++uu) {
    const int u = tid + uu * 512;          // 1024 units: 2 it x 8 q x 64 lanes
    const int lu = u & 63, g = u >> 6;
    const int q = g & 7, I = g >> 3;
    const float* p = x + (size_t)(r0 + I * 16 + (lu & 15)) * D_IN + q * 32 + ((lu >> 4) << 3);
    float4 a = *(const float4*)p, b = *(const float4*)(p + 4);
    short8 hh, mm;
    splitf8(a, b, hh, mm);
    const int off = ((I * 8 + q) * 64 + lu) * 8;
    *(short8*)(uAB.xp.h + off) = hh;
    *(short8*)(uAB.xp.m + off) = mm;
  }
  __syncthreads();

  // ---- layer1: h1 = tanh(x @ W1^T + b1), N=512; wave owns 4 j-tiles ----
  f32x4 acc1[2][4];
#pragma unroll
  for (int it = 0; it < 2; ++it)
#pragma unroll
    for (int jj = 0; jj < 4; ++jj) acc1[it][jj] = (f32x4){0.f, 0.f, 0.f, 0.f};

#pragma unroll 4
  for (int q = 0; q < 8; ++q) {
    short8 Ah[2], Am[2];
#pragma unroll
    for (int it = 0; it < 2; ++it) {
      const int off = ((it * 8 + q) * 64 + lane) * 8;
      Ah[it] = *(const short8*)(uAB.xp.h + off);
      Am[it] = *(const short8*)(uAB.xp.m + off);
    }
    short8 Bh[4], Bm[4];
#pragma unroll
    for (int jj = 0; jj < 4; ++jj) {
      const float* wp = W1 + (size_t)((wave * 4 + jj) * 16 + col16) * D_IN + q * 32 + k8;
      splitf8(*(const float4*)wp, *(const float4*)(wp + 4), Bh[jj], Bm[jj]);
    }
#pragma unroll
    for (int it = 0; it < 2; ++it)
#pragma unroll
      for (int jj = 0; jj < 4; ++jj) {
        acc1[it][jj] = __builtin_amdgcn_mfma_f32_16x16x32_bf16(Ah[it], Bh[jj], acc1[it][jj], 0, 0, 0);
        acc1[it][jj] = __builtin_amdgcn_mfma_f32_16x16x32_bf16(Ah[it], Bm[jj], acc1[it][jj], 0, 0, 0);
        acc1[it][jj] = __builtin_amdgcn_mfma_f32_16x16x32_bf16(Am[it], Bh[jj], acc1[it][jj], 0, 0, 0);
      }
  }

  // epilogue L1: two column-halves through wbuf (33 KB), tanh + split-pack
  float bv1[4];
#pragma unroll
  for (int jj = 0; jj < 4; ++jj) bv1[jj] = b1[(wave * 4 + jj) * 16 + col16];

#pragma unroll
  for (int h = 0; h < 2; ++h) {
    if ((wave >> 2) == h) {
#pragma unroll
      for (int it = 0; it < 2; ++it)
#pragma unroll
        for (int jj = 0; jj < 4; ++jj)
#pragma unroll
          for (int r = 0; r < 4; ++r) {
            const int row = it * 16 + rbase + r;
            const int col = ((wave & 3) * 4 + jj) * 16 + col16;   // [0,256)
            wbuf[row * WC + col] = tanh_fast(acc1[it][jj][r] + bv1[jj]);
          }
    }
    __syncthreads();
#pragma unroll
    for (int uu = 0; uu < 2; ++uu) {
      const int u = tid + uu * 512;        // 1024 units: 2 it x 8 q x 64 lanes
      const int lu = u & 63, g = u >> 6;
      const int ql = g & 7, it = g >> 3;
      const int row = it * 16 + (lu & 15);
      const int kl = ql * 32 + ((lu >> 4) << 3);
      const float* wp = &wbuf[row * WC + kl];
      short8 hh, mm;
      splitf8(*(const float4*)wp, *(const float4*)(wp + 4), hh, mm);
      const int off = ((it * 16 + h * 8 + ql) * 64 + lu) * 8;
      *(short8*)(h1h + off) = hh;
      *(short8*)(h1m + off) = mm;
    }
    __syncthreads();
  }

  // ---- layer2: h2 = tanh(h1 @ W2^T + b2), N=256; wave owns 2 j-tiles ----
  f32x4 acc2[2][2];
#pragma unroll
  for (int it = 0; it < 2; ++it)
#pragma unroll
    for (int jj = 0; jj < 2; ++jj) acc2[it][jj] = (f32x4){0.f, 0.f, 0.f, 0.f};

#pragma unroll 4
  for (int q = 0; q < 16; ++q) {
    short8 Ah[2], Am[2];
#pragma unroll
    for (int it = 0; it < 2; ++it) {
      const int off = ((it * 16 + q) * 64 + lane) * 8;
      Ah[it] = *(const short8*)(h1h + off);
      Am[it] = *(const short8*)(h1m + off);
    }
    short8 Bh[2], Bm[2];
#pragma unroll
    for (int jj = 0; jj < 2; ++jj) {
      const float* wp = W2 + (size_t)((wave * 2 + jj) * 16 + col16) * H1_DIM + q * 32 + k8;
      splitf8(*(const float4*)wp, *(const float4*)(wp + 4), Bh[jj], Bm[jj]);
    }
#pragma unroll
    for (int it = 0; it < 2; ++it)
#pragma unroll
      for (int jj = 0; jj < 2; ++jj) {
        acc2[it][jj] = __builtin_amdgcn_mfma_f32_16x16x32_bf16(Ah[it], Bh[jj], acc2[it][jj], 0, 0, 0);
        acc2[it][jj] = __builtin_amdgcn_mfma_f32_16x16x32_bf16(Ah[it], Bm[jj], acc2[it][jj], 0, 0, 0);
        acc2[it][jj] = __builtin_amdgcn_mfma_f32_16x16x32_bf16(Am[it], Bh[jj], acc2[it][jj], 0, 0, 0);
      }
  }

  // epilogue L2: all 256 cols fit wbuf in one pass
  {
    float bv2[2];
#pragma unroll
    for (int jj = 0; jj < 2; ++jj) bv2[jj] = b2[(wave * 2 + jj) * 16 + col16];
#pragma unroll
    for (int it = 0; it < 2; ++it)
#pragma unroll
      for (int jj = 0; jj < 2; ++jj)
#pragma unroll
        for (int r = 0; r < 4; ++r) {
          const int row = it * 16 + rbase + r;
          const int col = (wave * 2 + jj) * 16 + col16;
          wbuf[row * WC + col] = tanh_fast(acc2[it][jj][r] + bv2[jj]);
        }
  }
  __syncthreads();
#pragma unroll
  for (int uu = 0; uu < 2; ++uu) {
    const int u = tid + uu * 512;          // 1024 units: 2 it x 8 q x 64 lanes
    const int lu = u & 63, g = u >> 6;
    const int ql = g & 7, it = g >> 3;
    const int row = it * 16 + (lu & 15);
    const int kl = ql * 32 + ((lu >> 4) << 3);
    const float* wp = &wbuf[row * WC + kl];
    short8 hh, mm;
    splitf8(*(const float4*)wp, *(const float4*)(wp + 4), hh, mm);
    const int off = ((it * 8 + ql) * 64 + lu) * 8;   // xp region is dead now
    *(short8*)(uAB.h2p.h + off) = hh;
    *(short8*)(uAB.h2p.m + off) = mm;
  }
  __syncthreads();

  // ---- layer3: out = h2 @ W3^T + b3, N=64; waves 0-3 (one j-tile each) ----
  if (wave < 4) {
    f32x4 acc3[2];
#pragma unroll
    for (int it = 0; it < 2; ++it) acc3[it] = (f32x4){0.f, 0.f, 0.f, 0.f};
#pragma unroll
    for (int q = 0; q < 8; ++q) {
      short8 Ah[2], Am[2];
#pragma unroll
      for (int it = 0; it < 2; ++it) {
        const int off = ((it * 8 + q) * 64 + lane) * 8;
        Ah[it] = *(const short8*)(uAB.h2p.h + off);
        Am[it] = *(const short8*)(uAB.h2p.m + off);
      }
      short8 Bh, Bm;
      const float* wp = W3 + (size_t)(wave * 16 + col16) * H2_DIM + q * 32 + k8;
      splitf8(*(const float4*)wp, *(const float4*)(wp + 4), Bh, Bm);
#pragma unroll
      for (int it = 0; it < 2; ++it) {
        acc3[it] = __builtin_amdgcn_mfma_f32_16x16x32_bf16(Ah[it], Bh, acc3[it], 0, 0, 0);
        acc3[it] = __builtin_amdgcn_mfma_f32_16x16x32_bf16(Ah[it], Bm, acc3[it], 0, 0, 0);
        acc3[it] = __builtin_amdgcn_mfma_f32_16x16x32_bf16(Am[it], Bh, acc3[it], 0, 0, 0);
      }
    }
    const float bv3 = b3[wave * 16 + col16];
#pragma unroll
    for (int it = 0; it < 2; ++it)
#pragma unroll
      for (int r = 0; r < 4; ++r)
        wbuf[(it * 16 + rbase + r) * WC + wave * 16 + col16] = acc3[it][r] + bv3;
  }
  __syncthreads();

  // row norms: 8 threads per row, 8 cols each
  if (tid < 256) {
    const int row = tid >> 3, c0 = (tid & 7) * 8;
    const float* wp = &wbuf[row * WC + c0];
    float4 a = *(const float4*)wp, b = *(const float4*)(wp + 4);
    float s = a.x * a.x + a.y * a.y + a.z * a.z + a.w * a.w +
              b.x * b.x + b.y * b.y + b.z * b.z + b.w * b.w;
    s += __shfl_xor(s, 1, 64);
    s += __shfl_xor(s, 2, 64);
    s += __shfl_xor(s, 4, 64);
    if ((tid & 7) == 0) nsum[row] = s;
  }
  __syncthreads();
  if (tid < 32) invn[tid] = 1.0f / (sqrtf(nsum[tid]) + EPSF);
  __syncthreads();

  // write out (fp32)
  {
    const int row = tid >> 4, c4 = (tid & 15) * 4;
    *(float4*)(out + (size_t)(r0 + row) * D_OUT + c4) = *(const float4*)&wbuf[row * WC + c4];
  }
  // write normalized split-pack vph/vpm for the gram stage
  if (tid < 256) {
    const int lu = tid & 63, g = tid >> 6;   // 256 units: 2 it x 2 q x 64 lanes
    const int ql = g & 1, it = g >> 1;
    const int row = it * 16 + (lu & 15);
    const int kl = ql * 32 + ((lu >> 4) << 3);
    const float sc = invn[row];
    const float* wp = &wbuf[row * WC + kl];
    float4 a = *(const float4*)wp, b = *(const float4*)(wp + 4);
    a.x *= sc; a.y *= sc; a.z *= sc; a.w *= sc;
    b.x *= sc; b.y *= sc; b.z *= sc; b.w *= sc;
    short8 hh, mm;
    splitf8(a, b, hh, mm);
    const size_t off = (((size_t)(blockIdx.x * 2 + it) * 2 + ql) * 64 + lu) * 8;
    *(short8*)(vph + off) = hh;
    *(short8*)(vpm + off) = mm;
  }
}

// ---------------- MFMA Gram + threshold + sparse accumulate (v4, unchanged) ----------------
__global__ __launch_bounds__(256, 2)
void gram_accum(const short* __restrict__ vph, const short* __restrict__ vpm,
                const float* __restrict__ out, float* __restrict__ res) {
  __shared__ __align__(16) short lAh[8 * 1024];   // 16 KB: A hi, 8 i-tiles
  __shared__ __align__(16) short lAm[8 * 1024];   // 16 KB: A mid (refine only)
  const int tid = threadIdx.x;
  const int wave = tid >> 6, lane = tid & 63;

  // triangular decode: block t -> (I, Jc) with 0 <= I <= Jc < 64.
  const int t = blockIdx.x;
  int I = (int)((129.0f - sqrtf(16641.0f - 8.0f * (float)t)) * 0.5f);
  if (I < 0) I = 0;
  while (64 * (I + 1) - ((I + 1) * I) / 2 <= t) ++I;
  while (64 * I - (I * (I - 1)) / 2 > t) --I;
  const int Jc = I + (t - (64 * I - (I * (I - 1)) / 2));
  const int i0 = I * 128;    // 8 i-tiles
  const int j0c = Jc * 128;  // 8 j-tiles

  // stage A (hi+mid) for the 8 i-tiles into LDS
  {
    const size_t base = (size_t)I * 8192;
#pragma unroll
    for (int u = 0; u < 8; ++u) {
      const int item = wave * 8 + u;        // wave-uniform
      const short* src;
      short* dst;
      if (item < 16) { src = vph + base + item * 512; dst = lAh + item * 512; }
      else           { src = vpm + base + (item - 16) * 512; dst = lAm + (item - 16) * 512; }
      __builtin_amdgcn_global_load_lds(
          (const __attribute__((address_space(1))) void*)(src + lane * 8),
          (__attribute__((address_space(3))) void*)dst, 16, 0, 0);
    }
  }
  __syncthreads();

  short8 Ah[8][2];
#pragma unroll
  for (int it = 0; it < 8; ++it)
#pragma unroll
    for (int q = 0; q < 2; ++q)
      Ah[it][q] = *(const short8*)(lAh + it * 1024 + q * 512 + lane * 8);

#pragma unroll
  for (int tt = 0; tt < 2; ++tt) {
    const int jt = wave * 2 + tt;
    const int j0 = j0c + jt * 16;
    const short* jb_h = vph + (size_t)(j0 >> 4) * 1024;
    short8 Bh0 = *(const short8*)(jb_h + lane * 8);
    short8 Bh1 = *(const short8*)(jb_h + 512 + lane * 8);

    f32x4 g[8];
#pragma unroll
    for (int it = 0; it < 8; ++it) g[it] = (f32x4){0.f, 0.f, 0.f, 0.f};
#pragma unroll
    for (int it = 0; it < 8; ++it) g[it] = __builtin_amdgcn_mfma_f32_16x16x32_bf16(Ah[it][0], Bh0, g[it], 0, 0, 0);
#pragma unroll
    for (int it = 0; it < 8; ++it) g[it] = __builtin_amdgcn_mfma_f32_16x16x32_bf16(Ah[it][1], Bh1, g[it], 0, 0, 0);

    bool band = false;
#pragma unroll
    for (int it = 0; it < 8; ++it)
#pragma unroll
      for (int r = 0; r < 4; ++r) {
        const float f = g[it][r] * g[it][r];
        band = band || (f > BAND_LO && f < BAND_HI);
      }
    if (__any(band)) {
      const short* jb_m = vpm + (size_t)(j0 >> 4) * 1024;
      short8 Bm0 = *(const short8*)(jb_m + lane * 8);
      short8 Bm1 = *(const short8*)(jb_m + 512 + lane * 8);
#pragma unroll
      for (int it = 0; it < 8; ++it) g[it] = __builtin_amdgcn_mfma_f32_16x16x32_bf16(Ah[it][0], Bm0, g[it], 0, 0, 0);
#pragma unroll
      for (int it = 0; it < 8; ++it) g[it] = __builtin_amdgcn_mfma_f32_16x16x32_bf16(Ah[it][1], Bm1, g[it], 0, 0, 0);
#pragma unroll
      for (int it = 0; it < 8; ++it) {
        short8 Am0 = *(const short8*)(lAm + it * 1024 + lane * 8);
        short8 Am1 = *(const short8*)(lAm + it * 1024 + 512 + lane * 8);
        g[it] = __builtin_amdgcn_mfma_f32_16x16x32_bf16(Am0, Bh0, g[it], 0, 0, 0);
        g[it] = __builtin_amdgcn_mfma_f32_16x16x32_bf16(Am1, Bh1, g[it], 0, 0, 0);
      }
    }

    const int j = j0 + (lane & 15);
#pragma unroll
    for (int it = 0; it < 8; ++it) {
      const float m01 = fmaxf(g[it][0] * g[it][0], g[it][1] * g[it][1]);
      const float m23 = fmaxf(g[it][2] * g[it][2], g[it][3] * g[it][3]);
      if (fmaxf(m01, m23) >= THRESH) {
        const float* __restrict__ oj = out + (size_t)j * D_OUT;
#pragma unroll
        for (int r = 0; r < 4; ++r) {
          if (g[it][r] * g[it][r] >= THRESH) {
            const int i = i0 + it * 16 + (lane >> 4) * 4 + r;
            if (i < j) {
              float* __restrict__ ri = res + (size_t)i * D_OUT;
              float* __restrict__ rj = res + (size_t)j * D_OUT;
              const float* __restrict__ oi = out + (size_t)i * D_OUT;
              for (int k = 0; k < D_OUT; ++k) {
                atomicAdd(&ri[k], oj[k]);
                atomicAdd(&rj[k], oi[k]);
              }
            }
          }
        }
      }
    }
  }
}

// ---------------- launch ----------------
#define MB (1024 * 1024)

extern "C" void kernel_launch(void* const* d_in, const int* in_sizes, int n_in,
                              void* d_out, int out_size, void* d_ws, size_t ws_size,
                              hipStream_t stream) {
  const float* x  = (const float*)d_in[0];
  const float* W1 = (const float*)d_in[1];
  const float* b1 = (const float*)d_in[2];
  const float* W2 = (const float*)d_in[3];
  const float* b2 = (const float*)d_in[4];
  const float* W3 = (const float*)d_in[5];
  const float* b3 = (const float*)d_in[6];
  float* res = (float*)d_out;

  char* ws = (char*)d_ws;
  float* out = (float*)(ws);            // 2 MB
  short* vph = (short*)(ws + 2 * MB);   // 1 MB
  short* vpm = (short*)(ws + 3 * MB);   // 1 MB

  // one fused kernel: pack-x + 3 layers + norms + normalized vp + res zero
  fused_mlp<<<256, 512, 0, stream>>>(x, W1, b1, W2, b2, W3, b3, out, vph, vpm, res);
  // gram v4: triangular (Jc >= I) superblock pairs, hh-screen + rare refine
  gram_accum<<<dim3(2080), 256, 0, stream>>>(vph, vpm, out, res);
}

// Round 3
// 117.904 us; speedup vs baseline: 1.0952x; 1.0952x over previous
//
#include <hip/hip_runtime.h>
#include <hip/hip_bf16.h>
#include <math.h>

// Problem dims (fixed by reference)
#define B_ROWS 8192
#define D_IN   256
#define H1_DIM 512
#define H2_DIM 256
#define D_OUT  64
#define EPSF   1e-12f
#define THRESH 0.9f
// hh-only gram screen: |fid_hh - fid_true| < 0.008 for unit vectors
// -> decisions outside (0.89, 0.91) are certain; band hits get exact refine.
#define BAND_LO 0.89f
#define BAND_HI 0.91f

typedef __attribute__((ext_vector_type(8))) short short8;   // 8 bf16 = 4 VGPR
typedef __attribute__((ext_vector_type(4))) float f32x4;

// fast tanh via hardware exp: tanh(|x|) = (1-e^{-2|x|})/(1+e^{-2|x|}), ~1e-7 rel err
__device__ inline float tanh_fast(float xx) {
  const float ax = fabsf(xx);
  const float t = __expf(-2.0f * ax);
  const float r = (1.0f - t) / (1.0f + t);
  return xx < 0.0f ? -r : r;
}

// split fp32x8 -> bf16 hi + bf16 mid (residual), fragment-packed
__device__ inline void splitf8(float4 a, float4 b, short8& h, short8& m) {
  float v[8] = {a.x, a.y, a.z, a.w, b.x, b.y, b.z, b.w};
  short h8[8], m8[8];
#pragma unroll
  for (int e = 0; e < 8; ++e) {
    __hip_bfloat16 hb = __float2bfloat16(v[e]);
    float hf = __bfloat162float(hb);
    __hip_bfloat16 mb = __float2bfloat16(v[e] - hf);
    h8[e] = *(short*)&hb;
    m8[e] = *(short*)&mb;
  }
  h = *(short8*)h8;
  m = *(short8*)m8;
}

// read 8 logical-consecutive floats at (row, kl) from an XOR-swizzled LDS buf.
// swizzle: dword index ^= (row&7)<<2 (16B-slot spread -> conflict-free b128 reads)
__device__ inline void rd8_swz(const float* buf, int S, int row, int kl,
                               float4& a, float4& b) {
  const int xr = (row & 7) << 2;
  a = *(const float4*)&buf[(row * S + kl) ^ xr];
  b = *(const float4*)&buf[(row * S + kl + 4) ^ xr];
}

// ---------------- weight pre-pack (fragment-major bf16 hi/mid) ----------------
// frag layout (16x16x32 MFMA): tile I, kstep q, lane l, elem e
//   row = I*16 + (l&15), k = q*32 + (l>>4)*8 + e; flat index t*8+e
__device__ inline void pack8(const float* __restrict__ src, short* __restrict__ dh,
                             short* __restrict__ dm, int t, int C, int lgq) {
  const int lane = t & 63;
  const int g = t >> 6;
  const int q = g & ((1 << lgq) - 1);
  const int I = g >> lgq;
  const int row = I * 16 + (lane & 15);
  const int k0 = q * 32 + ((lane >> 4) << 3);
  const float* p = src + (size_t)row * C + k0;
  short8 hh, mm;
  splitf8(*(const float4*)p, *(const float4*)(p + 4), hh, mm);
  *(short8*)(dh + (size_t)t * 8) = hh;
  *(short8*)(dm + (size_t)t * 8) = mm;
}

__global__ __launch_bounds__(256)
void wpack(const float* __restrict__ W1, const float* __restrict__ W2,
           const float* __restrict__ W3,
           short* w1h, short* w1m, short* w2h, short* w2m,
           short* w3h, short* w3m) {
  const int b = blockIdx.x, tid = threadIdx.x;
  if (b < 64)        pack8(W1, w1h, w1m, b * 256 + tid, 256, 3);
  else if (b < 128)  pack8(W2, w2h, w2m, (b - 64) * 256 + tid, 512, 4);
  else               pack8(W3, w3h, w3m, (b - 128) * 256 + tid, 256, 3);
}

// ---------------- fully fused MLP, 16-row blocks ----------------
// 512 blocks x 16 rows, 8 waves (512 thr). LDS 48KB -> 2 blocks/CU (VGPR<=128),
// 16 waves/CU (2x round-2 occupancy). Weights pre-packed bf16 hi/mid ->
// K-loops are {short8 load (L2), ds_read A, MFMA} only — no splitf8 on the
// critical path. All transpose buffers XOR-swizzled (conflict-free b128).
// Fragment conventions (harness-verified in earlier rounds):
//   A/B frag: row = tile*16 + (lane&15), k = q*32 + (lane>>4)*8 + e
//   C/D:      row = (lane>>4)*4 + r (batch row), col = lane&15 (neuron)
__global__ __launch_bounds__(512, 4)
void fused_mlp16(const float* __restrict__ x,
                 const short* __restrict__ w1h, const short* __restrict__ w1m,
                 const float* __restrict__ b1,
                 const short* __restrict__ w2h, const short* __restrict__ w2m,
                 const float* __restrict__ b2,
                 const short* __restrict__ w3h, const short* __restrict__ w3m,
                 const float* __restrict__ b3,
                 float* __restrict__ out, short* __restrict__ vph,
                 short* __restrict__ vpm, float* __restrict__ res) {
  // 48KB LDS, phase-overlaid:
  //   [0,16K):   xp (L1 A-frags)  | wbuf1 (L1 epi, S=256) | wbuf3 (L3 epi, S=64)
  //   [16K,32K): h1h              | wbuf2 (L2 epi, S=256)
  //   [32K,48K): h1m              | h2ph+h2pm (L3 A-frags)
  __shared__ __align__(16) char smem[49152];
  short* xph   = (short*)smem;                // 8KB
  short* xpm   = (short*)(smem + 8192);       // 8KB
  float* wbuf1 = (float*)smem;                // 16KB
  float* wbuf3 = (float*)smem;                // 4KB
  short* h1h   = (short*)(smem + 16384);      // 16KB
  short* h1m   = (short*)(smem + 32768);      // 16KB
  float* wbuf2 = (float*)(smem + 16384);      // 16KB
  short* h2ph  = (short*)(smem + 32768);      // 8KB
  short* h2pm  = (short*)(smem + 40960);      // 8KB
  __shared__ float nsum[16];
  __shared__ float invn[16];

  const int tid = threadIdx.x;
  const int wave = tid >> 6, lane = tid & 63;
  const int r0 = blockIdx.x * 16;
  const int col16 = lane & 15;
  const int rbase = (lane >> 4) << 2;   // C-layout row base

  // zero this block's res rows (harness poisons res)
  if (tid < 256) {
    float4* rz = (float4*)(res + (size_t)r0 * D_OUT);
    rz[tid] = make_float4(0.f, 0.f, 0.f, 0.f);
  }

  // ---- pack x block (16x256 fp32 -> frag hi/mid): 512 units, 1/thread ----
  {
    const int lu = tid & 63, q = tid >> 6;
    const float* p = x + (size_t)(r0 + (lu & 15)) * D_IN + q * 32 + ((lu >> 4) << 3);
    short8 hh, mm;
    splitf8(*(const float4*)p, *(const float4*)(p + 4), hh, mm);
    const int off = (q * 64 + lu) * 8;
    *(short8*)(xph + off) = hh;
    *(short8*)(xpm + off) = mm;
  }
  __syncthreads();

  // ---- layer1: h1 = tanh(x @ W1^T + b1), N=512; wave owns 4 j-tiles ----
  f32x4 acc1[4];
#pragma unroll
  for (int jj = 0; jj < 4; ++jj) acc1[jj] = (f32x4){0.f, 0.f, 0.f, 0.f};
#pragma unroll 4
  for (int q = 0; q < 8; ++q) {
    const int aoff = (q * 64 + lane) * 8;
    const short8 Ah = *(const short8*)(xph + aoff);
    const short8 Am = *(const short8*)(xpm + aoff);
#pragma unroll
    for (int jj = 0; jj < 4; ++jj) {
      const int boff = (((wave * 4 + jj) * 8 + q) * 64 + lane) * 8;
      const short8 Bh = *(const short8*)(w1h + boff);
      const short8 Bm = *(const short8*)(w1m + boff);
      acc1[jj] = __builtin_amdgcn_mfma_f32_16x16x32_bf16(Ah, Bh, acc1[jj], 0, 0, 0);
      acc1[jj] = __builtin_amdgcn_mfma_f32_16x16x32_bf16(Ah, Bm, acc1[jj], 0, 0, 0);
      acc1[jj] = __builtin_amdgcn_mfma_f32_16x16x32_bf16(Am, Bh, acc1[jj], 0, 0, 0);
    }
  }
  __syncthreads();   // xp dead; [0,16K) becomes wbuf1

  // ---- L1 epilogue: two 256-col halves through swizzled wbuf1 ----
  float bv1[4];
#pragma unroll
  for (int jj = 0; jj < 4; ++jj) bv1[jj] = b1[(wave * 4 + jj) * 16 + col16];
#pragma unroll
  for (int h = 0; h < 2; ++h) {
    if ((wave >> 2) == h) {
#pragma unroll
      for (int jj = 0; jj < 4; ++jj)
#pragma unroll
        for (int r = 0; r < 4; ++r) {
          const int row = rbase + r;
          const int col = ((wave & 3) * 4 + jj) * 16 + col16;   // [0,256)
          wbuf1[(row * 256 + col) ^ ((row & 7) << 2)] = tanh_fast(acc1[jj][r] + bv1[jj]);
        }
    }
    __syncthreads();
    {
      const int lu = tid & 63, ql = tid >> 6;
      const int row = lu & 15, kl = ql * 32 + ((lu >> 4) << 3);
      float4 a, b;
      rd8_swz(wbuf1, 256, row, kl, a, b);
      short8 hh, mm;
      splitf8(a, b, hh, mm);
      const int off = ((h * 8 + ql) * 64 + lu) * 8;
      *(short8*)(h1h + off) = hh;
      *(short8*)(h1m + off) = mm;
    }
    __syncthreads();
  }

  // ---- layer2: h2 = tanh(h1 @ W2^T + b2), N=256; wave owns 2 j-tiles ----
  f32x4 acc2[2];
#pragma unroll
  for (int jj = 0; jj < 2; ++jj) acc2[jj] = (f32x4){0.f, 0.f, 0.f, 0.f};
#pragma unroll 4
  for (int q = 0; q < 16; ++q) {
    const int aoff = (q * 64 + lane) * 8;
    const short8 Ah = *(const short8*)(h1h + aoff);
    const short8 Am = *(const short8*)(h1m + aoff);
#pragma unroll
    for (int jj = 0; jj < 2; ++jj) {
      const int boff = (((wave * 2 + jj) * 16 + q) * 64 + lane) * 8;
      const short8 Bh = *(const short8*)(w2h + boff);
      const short8 Bm = *(const short8*)(w2m + boff);
      acc2[jj] = __builtin_amdgcn_mfma_f32_16x16x32_bf16(Ah, Bh, acc2[jj], 0, 0, 0);
      acc2[jj] = __builtin_amdgcn_mfma_f32_16x16x32_bf16(Ah, Bm, acc2[jj], 0, 0, 0);
      acc2[jj] = __builtin_amdgcn_mfma_f32_16x16x32_bf16(Am, Bh, acc2[jj], 0, 0, 0);
    }
  }
  __syncthreads();   // h1 dead; [16K,32K) becomes wbuf2

  // ---- L2 epilogue: one pass through swizzled wbuf2 ----
  {
    float bv2[2];
#pragma unroll
    for (int jj = 0; jj < 2; ++jj) bv2[jj] = b2[(wave * 2 + jj) * 16 + col16];
#pragma unroll
    for (int jj = 0; jj < 2; ++jj)
#pragma unroll
      for (int r = 0; r < 4; ++r) {
        const int row = rbase + r;
        const int col = (wave * 2 + jj) * 16 + col16;   // [0,256)
        wbuf2[(row * 256 + col) ^ ((row & 7) << 2)] = tanh_fast(acc2[jj][r] + bv2[jj]);
      }
  }
  __syncthreads();
  {
    const int lu = tid & 63, ql = tid >> 6;
    const int row = lu & 15, kl = ql * 32 + ((lu >> 4) << 3);
    float4 a, b;
    rd8_swz(wbuf2, 256, row, kl, a, b);
    short8 hh, mm;
    splitf8(a, b, hh, mm);
    const int off = (ql * 64 + lu) * 8;
    *(short8*)(h2ph + off) = hh;
    *(short8*)(h2pm + off) = mm;
  }
  __syncthreads();

  // ---- layer3: out = h2 @ W3^T + b3, N=64; waves 0-3 ----
  if (wave < 4) {
    f32x4 acc3 = (f32x4){0.f, 0.f, 0.f, 0.f};
#pragma unroll 4
    for (int q = 0; q < 8; ++q) {
      const int aoff = (q * 64 + lane) * 8;
      const short8 Ah = *(const short8*)(h2ph + aoff);
      const short8 Am = *(const short8*)(h2pm + aoff);
      const int boff = ((wave * 8 + q) * 64 + lane) * 8;
      const short8 Bh = *(const short8*)(w3h + boff);
      const short8 Bm = *(const short8*)(w3m + boff);
      acc3 = __builtin_amdgcn_mfma_f32_16x16x32_bf16(Ah, Bh, acc3, 0, 0, 0);
      acc3 = __builtin_amdgcn_mfma_f32_16x16x32_bf16(Ah, Bm, acc3, 0, 0, 0);
      acc3 = __builtin_amdgcn_mfma_f32_16x16x32_bf16(Am, Bh, acc3, 0, 0, 0);
    }
    const float bv3 = b3[wave * 16 + col16];
#pragma unroll
    for (int r = 0; r < 4; ++r) {
      const int row = rbase + r;
      const int col = wave * 16 + col16;   // [0,64)
      wbuf3[(row * 64 + col) ^ ((row & 7) << 2)] = acc3[r] + bv3;
    }
  }
  __syncthreads();

  // ---- row norms: 16 threads/row x 4 cols ----
  if (tid < 256) {
    const int row = tid >> 4, c4 = (tid & 15) * 4;
    const float4 a = *(const float4*)&wbuf3[(row * 64 + c4) ^ ((row & 7) << 2)];
    float s = a.x * a.x + a.y * a.y + a.z * a.z + a.w * a.w;
    s += __shfl_xor(s, 1, 64);
    s += __shfl_xor(s, 2, 64);
    s += __shfl_xor(s, 4, 64);
    s += __shfl_xor(s, 8, 64);
    if ((tid & 15) == 0) nsum[row] = s;
  }
  __syncthreads();
  if (tid < 16) invn[tid] = 1.0f / (sqrtf(nsum[tid]) + EPSF);
  __syncthreads();

  // ---- write out (fp32) ----
  if (tid < 256) {
    const int row = tid >> 4, c4 = (tid & 15) * 4;
    *(float4*)(out + (size_t)(r0 + row) * D_OUT + c4) =
        *(const float4*)&wbuf3[(row * 64 + c4) ^ ((row & 7) << 2)];
  }
  // ---- write normalized split-pack vph/vpm (gram A/B operand) ----
  if (tid < 128) {
    const int lu = tid & 63, ql = tid >> 6;
    const int row = lu & 15, kl = ql * 32 + ((lu >> 4) << 3);
    const float sc = invn[row];
    float4 a, b;
    rd8_swz(wbuf3, 64, row, kl, a, b);
    a.x *= sc; a.y *= sc; a.z *= sc; a.w *= sc;
    b.x *= sc; b.y *= sc; b.z *= sc; b.w *= sc;
    short8 hh, mm;
    splitf8(a, b, hh, mm);
    const size_t off = (((size_t)blockIdx.x * 2 + ql) * 64 + lu) * 8;
    *(short8*)(vph + off) = hh;
    *(short8*)(vpm + off) = mm;
  }
}

// ---------------- MFMA Gram + threshold + wave-cooperative scatter (v5) ----------------
// res[i] = sum_{j != i, (v_i.v_j)^2 >= 0.9} out[j]
// v5 changes vs v4: (a) ballot-scatter — per (it,r), __ballot the passing
//     lanes, then ALL 64 lanes cooperatively scatter each pair (lane k adds
//     element k): 2 coalesced atomics/lane/pair instead of 128 serial atomics
//     on one lane.  (b) no lAm stage — refine (rare) reads A-mid from global.
__global__ __launch_bounds__(256, 2)
void gram_accum(const short* __restrict__ vph, const short* __restrict__ vpm,
                const float* __restrict__ out, float* __restrict__ res) {
  __shared__ __align__(16) short lAh[8 * 1024];   // 16 KB: A hi, 8 i-tiles
  const int tid = threadIdx.x;
  const int wave = tid >> 6, lane = tid & 63;

  // triangular decode: block t -> (I, Jc) with 0 <= I <= Jc < 64
  const int t = blockIdx.x;
  int I = (int)((129.0f - sqrtf(16641.0f - 8.0f * (float)t)) * 0.5f);
  if (I < 0) I = 0;
  while (64 * (I + 1) - ((I + 1) * I) / 2 <= t) ++I;
  while (64 * I - (I * (I - 1)) / 2 > t) --I;
  const int Jc = I + (t - (64 * I - (I * (I - 1)) / 2));
  const int i0 = I * 128;    // 8 i-tiles
  const int j0c = Jc * 128;  // 8 j-tiles

  // stage A-hi for the 8 i-tiles (16 KB): 16 wave-uniform 1KB items
  {
    const size_t base = (size_t)I * 8192;
#pragma unroll
    for (int u = 0; u < 4; ++u) {
      const int item = wave * 4 + u;
      __builtin_amdgcn_global_load_lds(
          (const __attribute__((address_space(1))) void*)(vph + base + item * 512 + lane * 8),
          (__attribute__((address_space(3))) void*)(lAh + item * 512), 16, 0, 0);
    }
  }
  __syncthreads();

  short8 Ah[8][2];
#pragma unroll
  for (int it = 0; it < 8; ++it)
#pragma unroll
    for (int q = 0; q < 2; ++q)
      Ah[it][q] = *(const short8*)(lAh + it * 1024 + q * 512 + lane * 8);

#pragma unroll
  for (int tt = 0; tt < 2; ++tt) {
    const int jt = wave * 2 + tt;
    const int j0 = j0c + jt * 16;
    const short* jb_h = vph + (size_t)(j0 >> 4) * 1024;
    short8 Bh0 = *(const short8*)(jb_h + lane * 8);
    short8 Bh1 = *(const short8*)(jb_h + 512 + lane * 8);

    f32x4 g[8];
#pragma unroll
    for (int it = 0; it < 8; ++it) g[it] = (f32x4){0.f, 0.f, 0.f, 0.f};
    // hh screen: 16 MFMAs, 8 independent chains
#pragma unroll
    for (int it = 0; it < 8; ++it) g[it] = __builtin_amdgcn_mfma_f32_16x16x32_bf16(Ah[it][0], Bh0, g[it], 0, 0, 0);
#pragma unroll
    for (int it = 0; it < 8; ++it) g[it] = __builtin_amdgcn_mfma_f32_16x16x32_bf16(Ah[it][1], Bh1, g[it], 0, 0, 0);

    bool band = false;
#pragma unroll
    for (int it = 0; it < 8; ++it)
#pragma unroll
      for (int r = 0; r < 4; ++r) {
        const float f = g[it][r] * g[it][r];
        band = band || (f > BAND_LO && f < BAND_HI);
      }
    if (__any(band)) {
      // exact refine: add hi*mid + mid*hi terms (A-mid straight from global)
      const short* jb_m = vpm + (size_t)(j0 >> 4) * 1024;
      short8 Bm0 = *(const short8*)(jb_m + lane * 8);
      short8 Bm1 = *(const short8*)(jb_m + 512 + lane * 8);
#pragma unroll
      for (int it = 0; it < 8; ++it) g[it] = __builtin_amdgcn_mfma_f32_16x16x32_bf16(Ah[it][0], Bm0, g[it], 0, 0, 0);
#pragma unroll
      for (int it = 0; it < 8; ++it) g[it] = __builtin_amdgcn_mfma_f32_16x16x32_bf16(Ah[it][1], Bm1, g[it], 0, 0, 0);
#pragma unroll
      for (int it = 0; it < 8; ++it) {
        const size_t abase = (size_t)((i0 >> 4) + it) * 1024;
        short8 Am0 = *(const short8*)(vpm + abase + lane * 8);
        short8 Am1 = *(const short8*)(vpm + abase + 512 + lane * 8);
        g[it] = __builtin_amdgcn_mfma_f32_16x16x32_bf16(Am0, Bh0, g[it], 0, 0, 0);
        g[it] = __builtin_amdgcn_mfma_f32_16x16x32_bf16(Am1, Bh1, g[it], 0, 0, 0);
      }
    }

    // ballot + wave-cooperative mirrored scatter (i < j only)
    const int jl = j0 + (lane & 15);
#pragma unroll
    for (int it = 0; it < 8; ++it)
#pragma unroll
      for (int r = 0; r < 4; ++r) {
        const int il = i0 + it * 16 + (lane >> 4) * 4 + r;
        unsigned long long m =
            __ballot((g[it][r] * g[it][r] >= THRESH) && (il < jl));
        while (m) {
          const int s = __builtin_ctzll(m);
          m &= m - 1;
          const int js = j0 + (s & 15);
          const int is = i0 + it * 16 + ((s >> 4) << 2) + r;
          atomicAdd(res + (size_t)is * D_OUT + lane, out[(size_t)js * D_OUT + lane]);
          atomicAdd(res + (size_t)js * D_OUT + lane, out[(size_t)is * D_OUT + lane]);
        }
      }
  }
}

// ---------------- launch ----------------
#define MB (1024 * 1024)
#define KB 1024

extern "C" void kernel_launch(void* const* d_in, const int* in_sizes, int n_in,
                              void* d_out, int out_size, void* d_ws, size_t ws_size,
                              hipStream_t stream) {
  const float* x  = (const float*)d_in[0];
  const float* W1 = (const float*)d_in[1];
  const float* b1 = (const float*)d_in[2];
  const float* W2 = (const float*)d_in[3];
  const float* b2 = (const float*)d_in[4];
  const float* W3 = (const float*)d_in[5];
  const float* b3 = (const float*)d_in[6];
  float* res = (float*)d_out;

  char* ws = (char*)d_ws;
  float* out = (float*)(ws);                     // 2 MB
  short* vph = (short*)(ws + 2 * MB);            // 1 MB
  short* vpm = (short*)(ws + 3 * MB);            // 1 MB
  short* w1h = (short*)(ws + 4 * MB);            // 256 KB
  short* w1m = (short*)(ws + 4 * MB + 256 * KB);
  short* w2h = (short*)(ws + 4 * MB + 512 * KB);
  short* w2m = (short*)(ws + 4 * MB + 768 * KB);
  short* w3h = (short*)(ws + 5 * MB);            // 32 KB
  short* w3m = (short*)(ws + 5 * MB + 32 * KB);

  // pack weights to fragment-major bf16 hi/mid (tiny, ~2.2 MB rw)
  wpack<<<136, 256, 0, stream>>>(W1, W2, W3, w1h, w1m, w2h, w2m, w3h, w3m);
  // fused MLP: 512 x 16-row blocks, 2 blocks/CU
  fused_mlp16<<<512, 512, 0, stream>>>(x, w1h, w1m, b1, w2h, w2m, b2,
                                       w3h, w3m, b3, out, vph, vpm, res);
  // gram v5: triangular superblocks, hh-screen + rare refine, ballot scatter
  gram_accum<<<dim3(2080), 256, 0, stream>>>(vph, vpm, out, res);
}